// Round 18
// baseline (78.325 us; speedup 1.0000x reference)
//
#include <hip/hip_runtime.h>

#define S 256
#define L2E 1.44269504088896340736f   // log2(e)
#define LN2 0.69314718055994530942f

// Raw HW transcendentals: v_exp_f32 = 2^x, v_log_f32 = log2(x).
#define EXP2F(x) __builtin_amdgcn_exp2f(x)
#define LOG2F(x) __builtin_amdgcn_logf(x)

// Probability-domain soft-min DP (R17 machine verbatim) with LINE-BURST
// loading: each row's four slot-quads (one 64B line's worth, cols base
// +0/+4/+8/+12) are loaded back-to-back at the row's SB==0 step, instead
// of one slot per step.  R17 post-mortem: per-step divergent gathers made
// every quad-touch an L1 miss (64 lines/step/wave; 2-wave footprint 32KB =
// L1 size -> thrash), saturating the L2 request path (~103 req/cy vs ~128
// capacity).  Burst-adjacency makes quads 2-4 of each line guaranteed L1
// hits -> ~4x fewer L2 requests.  Load->convert distance stays 16 steps.
// Conversion cols, junk masks, renorm, seed, output: identical to R17
// (verified absmax 0).

template <int I> __device__ __forceinline__ float comp(const float4& v) {
    if constexpr (I == 0) return v.x;
    else if constexpr (I == 1) return v.y;
    else if constexpr (I == 2) return v.z;
    else return v.w;
}

__device__ __forceinline__ float4 g4f(const float4& v) {
    float4 r;
    r.x = EXP2F(v.x * -L2E); r.y = EXP2F(v.y * -L2E);
    r.z = EXP2F(v.z * -L2E); r.w = EXP2F(v.w * -L2E);
    return r;
}

template <int P, int SB>
__device__ __forceinline__ void stepf(
    int kk, int t, int t4, const float* __restrict__ Cb,
    int rb0, int rb1, int rb2, int rb3,
    float4& c0, float4& c1, float4& c2, float4& c3,
    float4& n0, float4& n1, float4& n2, float4& n3,
    float4& s00, float4& s01, float4& s02, float4& s03,
    float4& s10, float4& s11, float4& s12, float4& s13,
    float4& s20, float4& s21, float4& s22, float4& s23,
    float4& s30, float4& s31, float4& s32, float4& s33,
    float& w10, float& w11, float& w12, float& w13,
    float& w20, float& w21, float& w22, float& w23,
    float& pd1, float& pd2)
{
    const int colr = kk + (20 - P) - t4;
    const int rb   = (P == 0) ? rb0 : (P == 1) ? rb1 : (P == 2) ? rb2 : rb3;

    float4& cP = (P == 0) ? c0 : (P == 1) ? c1 : (P == 2) ? c2 : c3;
    float4& nP = (P == 0) ? n0 : (P == 1) ? n1 : (P == 2) ? n2 : n3;
    float4& sP =
        (SB == 0) ? ((P == 0) ? s00 : (P == 1) ? s01 : (P == 2) ? s02 : s03)
      : (SB == 1) ? ((P == 0) ? s10 : (P == 1) ? s11 : (P == 2) ? s12 : s13)
      : (SB == 2) ? ((P == 0) ? s20 : (P == 1) ? s21 : (P == 2) ? s22 : s23)
                  : ((P == 0) ? s30 : (P == 1) ? s31 : (P == 2) ? s32 : s33);

    // convert the slot loaded 16 steps ago; zero it if its col was clamped
    const bool junk = (colr > 268);
    float4 gq;
    gq.x = junk ? 0.0f : EXP2F(sP.x * -L2E);
    gq.y = junk ? 0.0f : EXP2F(sP.y * -L2E);
    gq.z = junk ? 0.0f : EXP2F(sP.z * -L2E);
    gq.w = junk ? 0.0f : EXP2F(sP.w * -L2E);
    cP = nP;
    nP = gq;

    if constexpr (SB == 0) {
        // line-burst refill of row P's 4 slots: cols colr+0/+4/+8/+12
        // (consumed at steps kk+16, kk+20, kk+24, kk+28)
        auto clm = [](int c) { return c < 0 ? 0 : (c > 252 ? 252 : c); };
        float4& bA = (P == 0) ? s00 : (P == 1) ? s01 : (P == 2) ? s02 : s03;
        float4& bB = (P == 0) ? s10 : (P == 1) ? s11 : (P == 2) ? s12 : s13;
        float4& bC = (P == 0) ? s20 : (P == 1) ? s21 : (P == 2) ? s22 : s23;
        float4& bD = (P == 0) ? s30 : (P == 1) ? s31 : (P == 2) ? s32 : s33;
        bA = *(const float4*)(Cb + rb + clm(colr));
        bB = *(const float4*)(Cb + rb + clm(colr + 4));
        bC = *(const float4*)(Cb + rb + clm(colr + 8));
        bD = *(const float4*)(Cb + rb + clm(colr + 12));
    }

    const float g0 = comp<(P    ) & 3>(c0);
    const float g1 = comp<(P + 3) & 3>(c1);
    const float g2 = comp<(P + 2) & 3>(c2);
    const float g3 = comp<(P + 1) & 3>(c3);

    const float e0 = g0 * (w10 + pd1 + pd2);
    const float e1 = g1 * (w11 + w10 + w20);
    const float e2 = g2 * (w12 + w11 + w21);
    const float e3 = g3 * (w13 + w12 + w22);

    w20 = w10; w21 = w11; w22 = w12; w23 = w13;
    w10 = e0;  w11 = e1;  w12 = e2;  w13 = e3;

    const float nx = __shfl_up(e3, 1);
    pd2 = pd1;
    pd1 = (t == 0) ? 0.0f : nx;

    // step boundary: loads may not cross a may-store asm (no insts emitted)
    asm volatile("" ::: "memory");
}

__global__ __launch_bounds__(64, 1) void dp_softmin_wave(const float* __restrict__ C,
                                                         float* __restrict__ out) {
    const int b = blockIdx.x;
    const int t = threadIdx.x;
    const float* Cb = C + ((size_t)b << 16);
    const int t4 = 4 * t;

    const int rb0 = (t4 + 0) << 8;
    const int rb1 = (t4 + 1) << 8;
    const int rb2 = (t4 + 2) << 8;
    const int rb3 = (t4 + 3) << 8;

    auto cl = [](int c) { return c < 0 ? 0 : (c > 252 ? 252 : c); };
    auto q4 = [&](int rb, int col) { return *(const float4*)(Cb + rb + col); };

    // init = fixed point of the unconditional machine for kk <= 0 (R12)
    float4 c0 = g4f(q4(rb0, 0)), c1 = g4f(q4(rb1, 0)),
           c2 = g4f(q4(rb2, 0)), c3 = g4f(q4(rb3, 0));
    float4 n0 = g4f(q4(rb0, cl(4 - t4)));
    float4 n1 = c1, n2 = c2, n3 = c3;

    // slot preloads (same cols as R17, grouped per row = line-adjacent)
    float4 s01 = q4(rb1, cl(4 - t4)),  s11 = q4(rb1, cl(8 - t4));
    float4 s21 = q4(rb1, cl(12 - t4)), s31 = q4(rb1, cl(16 - t4));
    float4 s02 = q4(rb2, cl(4 - t4)),  s12 = q4(rb2, cl(8 - t4));
    float4 s22 = q4(rb2, cl(12 - t4)), s32 = q4(rb2, cl(16 - t4));
    float4 s03 = q4(rb3, cl(4 - t4)),  s13 = q4(rb3, cl(8 - t4));
    float4 s23 = q4(rb3, cl(12 - t4)), s33 = q4(rb3, cl(16 - t4));
    float4 s10 = q4(rb0, cl(8 - t4)),  s20 = q4(rb0, cl(12 - t4));
    float4 s30 = q4(rb0, cl(16 - t4)), s00 = q4(rb0, cl(20 - t4));

    float w10 = 0.0f, w11 = 0.0f, w12 = 0.0f, w13 = 0.0f;
    float w20 = 0.0f, w21 = 0.0f, w22 = 0.0f, w23 = 0.0f;
    float pd1 = 0.0f, pd2 = 0.0f;
    int sig = 0;

    if (t == 0) w10 = c0.x;                // seed: w(0,0) = g(0,0)

    asm volatile("" ::: "memory");          // pin init loads above the chain

#define ARGS t, t4, Cb, rb0, rb1, rb2, rb3, c0,c1,c2,c3, n0,n1,n2,n3, \
             s00,s01,s02,s03, s10,s11,s12,s13, s20,s21,s22,s23, s30,s31,s32,s33, \
             w10,w11,w12,w13, w20,w21,w22,w23, pd1,pd2

    // prologue kk = 1..15
    stepf<1,0>(1, ARGS);  stepf<2,0>(2, ARGS);  stepf<3,0>(3, ARGS);
    stepf<0,1>(4, ARGS);  stepf<1,1>(5, ARGS);  stepf<2,1>(6, ARGS);  stepf<3,1>(7, ARGS);
    stepf<0,2>(8, ARGS);  stepf<1,2>(9, ARGS);  stepf<2,2>(10, ARGS); stepf<3,2>(11, ARGS);
    stepf<0,3>(12, ARGS); stepf<1,3>(13, ARGS); stepf<2,3>(14, ARGS); stepf<3,3>(15, ARGS);

#pragma clang loop unroll(disable)
    for (int kb = 16; kb <= 480; kb += 16) {
        if ((kb & 63) == 0) {
            // block-floating renorm: exact power-of-2, sig -= e
            float M = fmaxf(fmaxf(fmaxf(w10, w11), fmaxf(w12, w13)),
                            fmaxf(fmaxf(w20, w21), fmaxf(w22, w23)));
            #pragma unroll
            for (int m = 1; m < 64; m <<= 1) M = fmaxf(M, __shfl_xor(M, m));
            int e = ((__float_as_int(M) >> 23) & 255) - 127;
            float f = __int_as_float((127 - e) << 23);
            w10 *= f; w11 *= f; w12 *= f; w13 *= f;
            w20 *= f; w21 *= f; w22 *= f; w23 *= f;
            pd1 *= f; pd2 *= f;
            sig -= e;
        }
        stepf<0,0>(kb + 0, ARGS);  stepf<1,0>(kb + 1, ARGS);
        stepf<2,0>(kb + 2, ARGS);  stepf<3,0>(kb + 3, ARGS);
        stepf<0,1>(kb + 4, ARGS);  stepf<1,1>(kb + 5, ARGS);
        stepf<2,1>(kb + 6, ARGS);  stepf<3,1>(kb + 7, ARGS);
        stepf<0,2>(kb + 8, ARGS);  stepf<1,2>(kb + 9, ARGS);
        stepf<2,2>(kb + 10, ARGS); stepf<3,2>(kb + 11, ARGS);
        stepf<0,3>(kb + 12, ARGS); stepf<1,3>(kb + 13, ARGS);
        stepf<2,3>(kb + 14, ARGS); stepf<3,3>(kb + 15, ARGS);
    }

    // epilogue kk = 496..510
    stepf<0,0>(496, ARGS); stepf<1,0>(497, ARGS); stepf<2,0>(498, ARGS); stepf<3,0>(499, ARGS);
    stepf<0,1>(500, ARGS); stepf<1,1>(501, ARGS); stepf<2,1>(502, ARGS); stepf<3,1>(503, ARGS);
    stepf<0,2>(504, ARGS); stepf<1,2>(505, ARGS); stepf<2,2>(506, ARGS); stepf<3,2>(507, ARGS);
    stepf<0,3>(508, ARGS); stepf<1,3>(509, ARGS); stepf<2,3>(510, ARGS);
#undef ARGS

    // corner cell (255,255): lane 63, E = sig - log2(w13), D = E * ln2
    if (t == 63) out[b] = ((float)sig - LOG2F(w13)) * LN2;
}

extern "C" void kernel_launch(void* const* d_in, const int* in_sizes, int n_in,
                              void* d_out, int out_size, void* d_ws, size_t ws_size,
                              hipStream_t stream) {
    const float* C = (const float*)d_in[0];
    float* out = (float*)d_out;
    dp_softmin_wave<<<512, 64, 0, stream>>>(C, out);
}

// Round 19
// 70.341 us; speedup vs baseline: 1.1135x; 1.1135x over previous
//
#include <hip/hip_runtime.h>

#define L2E 1.44269504088896340736f   // log2(e)
#define LN2 0.69314718055994530942f

// Raw HW transcendentals: v_exp_f32 = 2^x, v_log_f32 = log2(x).
#define EXP2F(x) __builtin_amdgcn_exp2f(x)
#define LOG2F(x) __builtin_amdgcn_logf(x)

// Probability-domain soft-min DP with LDS-staged cost matrix.
// R18 post-mortem: the wall is vector-memory ADDRESS processing -- every
// divergent load touches 64 distinct lines (rows 1KB apart), ~2.5cy/line
// shared per CU => ~320cy/step regardless of depth/pinning (R14: two DPs
// in one wave ran exactly 2x => stall is consumed, not idle).  Fix: stage
// C through LDS windows with 16-line coalesced loads (4x fewer line-addrs),
// then per-step ds_read_b128 (bank-spread by the diagonal + (q+g)&3 quad
// rotation).  Compute core = R17 verbatim (verified absmax 0).
//
// LDS: 4-slot ring x 16 groups x [16 rows][16 cols] f32 = 64KB.
// Window (G,w) = rows 16G..16G+15 x cols 16w..16w+15, slot = w&3,
// float base = ((w&3)*16+G)*256; row a holds quads at phys ((q+G)&3).
// Staging schedule (flat step counter m): LOAD(m) = window (m&15,
// clamp((m>>4)+2-(m&15),0,15)) into ring reg L[m&3]; WRITE at m+4.
// Margins (hand-verified): write >= 5 steps before first read-issue;
// overwrite >= 10 steps after last read; same-wave DS FIFO orders the rest.
// Pre-staged upfront: (0,0),(0,1),(1,0); ring preloads m=-3..0 =
// (13,0),(14,0),(15,0),(0,2).  RQ_P = ds_read issued 4 steps ahead of its
// conversion (u = kk+4-r, quad-aligned); ok-mask (u==clamp(u)) zeroes
// junk AND any unstaged-garbage reads.  Renorm every 64 diags (2^-e exact,
// sig -= e).  One wave per batch; no barriers.

typedef float f4 __attribute__((ext_vector_type(4)));

template <int I> __device__ __forceinline__ float comp(const f4 v) {
    if constexpr (I == 0) return v.x;
    else if constexpr (I == 1) return v.y;
    else if constexpr (I == 2) return v.z;
    else return v.w;
}

__device__ __forceinline__ f4 g4f(const f4 v) {
    f4 r;
    r.x = EXP2F(v.x * -L2E); r.y = EXP2F(v.y * -L2E);
    r.z = EXP2F(v.z * -L2E); r.w = EXP2F(v.w * -L2E);
    return r;
}

template <int J, bool STAGE, bool RQF>
__device__ __forceinline__ void stepf(
    int kb, int sg, int sgm1,
    int t, int t4, int g,
    const float* __restrict__ Cb, float* lds,
    int baseR, int glane, int wl0, int wl1, int wl2, int wl3,
    f4& c0, f4& c1, f4& c2, f4& c3,
    f4& n0, f4& n1, f4& n2, f4& n3,
    f4& L0, f4& L1, f4& L2, f4& L3,
    f4& RQ0, f4& RQ1, f4& RQ2, f4& RQ3,
    float& w10, float& w11, float& w12, float& w13,
    float& w20, float& w21, float& w22, float& w23,
    float& pd1, float& pd2)
{
    constexpr int P = J & 3;      // phase; ring index J&3 == P

    f4& cP  = (P == 0) ? c0 : (P == 1) ? c1 : (P == 2) ? c2 : c3;
    f4& nP  = (P == 0) ? n0 : (P == 1) ? n1 : (P == 2) ? n2 : n3;
    f4& LR  = (P == 0) ? L0 : (P == 1) ? L1 : (P == 2) ? L2 : L3;
    f4& RQP = (P == 0) ? RQ0 : (P == 1) ? RQ1 : (P == 2) ? RQ2 : RQ3;

    // ---- conversion of RQP (ds_read issued 4 steps ago, u = kk+4-rP)
    const int u  = (kb + J + 4 - P) - t4;
    const int uc = u < 0 ? 0 : (u > 252 ? 252 : u);
    const bool ok = (u == uc);
    f4 gq;
    gq.x = ok ? EXP2F(RQP.x * -L2E) : 0.0f;
    gq.y = ok ? EXP2F(RQP.y * -L2E) : 0.0f;
    gq.z = ok ? EXP2F(RQP.z * -L2E) : 0.0f;
    gq.w = ok ? EXP2F(RQP.w * -L2E) : 0.0f;
    cP = nP;
    nP = gq;

    // ---- staging: write ring reg loaded 4 steps ago, then refill it
    if constexpr (STAGE) {
        constexpr int WG = (J >= 4) ? J - 4 : J + 12;
        const int wsv = (J >= 4) ? sg : sgm1;
        int ww = wsv - WG; ww = ww < 0 ? 0 : (ww > 15 ? 15 : ww);
        const int wlP = (P == 0) ? wl0 : (P == 1) ? wl1 : (P == 2) ? wl2 : wl3;
        *(f4*)(lds + ((ww & 3) * 16 + WG) * 256 + wlP) = LR;
        int wl = sg - J; wl = wl < 0 ? 0 : (wl > 15 ? 15 : wl);
        LR = *(const f4*)(Cb + J * 4096 + wl * 16 + glane);
    }

    // ---- cells (R17 verbatim)
    const float g0 = comp<(P    ) & 3>(c0);
    const float g1 = comp<(P + 3) & 3>(c1);
    const float g2 = comp<(P + 2) & 3>(c2);
    const float g3 = comp<(P + 1) & 3>(c3);
    const float e0 = g0 * (w10 + pd1 + pd2);
    const float e1 = g1 * (w11 + w10 + w20);
    const float e2 = g2 * (w12 + w11 + w21);
    const float e3 = g3 * (w13 + w12 + w22);
    w20 = w10; w21 = w11; w22 = w12; w23 = w13;
    w10 = e0;  w11 = e1;  w12 = e2;  w13 = e3;

    const float nx = __shfl_up(e3, 1);
    pd2 = pd1;
    pd1 = (t == 0) ? 0.0f : nx;

    // bperm above / RQ refill below: keeps the in-order lgkmcnt wait for
    // the shfl from draining the fresh ds_read (emits no instructions)
    asm volatile("" ::: "memory");

    // ---- RQ refill for step kk+4
    if constexpr (RQF) {
        const int u2  = (kb + J + 8 - P) - t4;
        const int uc2 = u2 < 0 ? 0 : (u2 > 252 ? 252 : u2);
        const int s2  = (uc2 >> 4) & 3;
        const int pq  = ((uc2 >> 2) + g) & 3;
        RQP = *(const f4*)(lds + s2 * 4096 + baseR + 16 * P + pq * 4);
    }
    asm volatile("" ::: "memory");
}

__global__ __launch_bounds__(64, 1) void dp_softmin_wave(const float* __restrict__ C,
                                                         float* __restrict__ out) {
    const int b = blockIdx.x;
    const int t = threadIdx.x;
    const float* Cb = C + ((size_t)b << 16);
    const int t4 = 4 * t;
    const int g  = t >> 2;                       // row-group of this lane's rows

    __shared__ float ldsmem[16384];              // 64 KB
    float* lds = ldsmem;

    // lane consts
    const int baseR = g * 256 + 64 * (t & 3);    // + 16P + pq*4 at read time
    const int glane = (t >> 2) * 256 + (t & 3) * 4;          // stage-load lane part
    const int wl0 = (t >> 2) * 16 + (((t & 3) + 0) & 3) * 4; // stage-write lane parts
    const int wl1 = (t >> 2) * 16 + (((t & 3) + 1) & 3) * 4;
    const int wl2 = (t >> 2) * 16 + (((t & 3) + 2) & 3) * 4;
    const int wl3 = (t >> 2) * 16 + (((t & 3) + 3) & 3) * 4;

    // ---- c/n init: R17 fixed-point (direct one-time loads)
    auto cl = [](int c) { return c < 0 ? 0 : (c > 252 ? 252 : c); };
    auto q4 = [&](int rb, int col) { return *(const f4*)(Cb + rb + col); };
    const int rb0 = (t4 + 0) << 8, rb1 = (t4 + 1) << 8,
              rb2 = (t4 + 2) << 8, rb3 = (t4 + 3) << 8;
    f4 c0 = g4f(q4(rb0, 0)), c1 = g4f(q4(rb1, 0)),
       c2 = g4f(q4(rb2, 0)), c3 = g4f(q4(rb3, 0));
    f4 n0 = g4f(q4(rb0, cl(4 - t4)));
    f4 n1 = c1, n2 = c2, n3 = c3;

    // ---- pre-stage windows (0,0), (0,1), (1,0)
    {
        f4 a0 = *(const f4*)(Cb + 0 * 4096 + 0 * 16 + glane);
        f4 a1 = *(const f4*)(Cb + 0 * 4096 + 1 * 16 + glane);
        f4 a2 = *(const f4*)(Cb + 1 * 4096 + 0 * 16 + glane);
        *(f4*)(lds + (0 * 16 + 0) * 256 + wl0) = a0;   // (0,0) slot 0
        *(f4*)(lds + (1 * 16 + 0) * 256 + wl0) = a1;   // (0,1) slot 1
        *(f4*)(lds + (0 * 16 + 1) * 256 + wl1) = a2;   // (1,0) slot 0
    }

    // ---- ring preloads m=-3..0: (13,0)->L1, (14,0)->L2, (15,0)->L3, (0,2)->L0
    f4 L1 = *(const f4*)(Cb + 13 * 4096 + glane);
    f4 L2 = *(const f4*)(Cb + 14 * 4096 + glane);
    f4 L3 = *(const f4*)(Cb + 15 * 4096 + glane);
    f4 L0 = *(const f4*)(Cb + 0 * 4096 + 2 * 16 + glane);

    // ---- RQ preloads for consume steps kk = 1..4 (phases 1,2,3,0)
    auto rqpre = [&](int kk, int Pp) -> f4 {
        int u2  = (kk + 4 - Pp) - t4;
        int uc2 = u2 < 0 ? 0 : (u2 > 252 ? 252 : u2);
        int s2  = (uc2 >> 4) & 3;
        int pq  = ((uc2 >> 2) + g) & 3;
        return *(const f4*)(lds + s2 * 4096 + baseR + 16 * Pp + pq * 4);
    };
    f4 RQ1 = rqpre(1, 1), RQ2 = rqpre(2, 2), RQ3 = rqpre(3, 3), RQ0 = rqpre(4, 0);

    float w10 = 0.0f, w11 = 0.0f, w12 = 0.0f, w13 = 0.0f;
    float w20 = 0.0f, w21 = 0.0f, w22 = 0.0f, w23 = 0.0f;
    float pd1 = 0.0f, pd2 = 0.0f;
    int sig = 0;
    if (t == 0) w10 = c0.x;                      // seed: w(0,0) = g(0,0)

#define ARGS t, t4, g, Cb, lds, baseR, glane, wl0, wl1, wl2, wl3, \
             c0,c1,c2,c3, n0,n1,n2,n3, L0,L1,L2,L3, RQ0,RQ1,RQ2,RQ3, \
             w10,w11,w12,w13, w20,w21,w22,w23, pd1,pd2

    // ---- prologue kk = 1..15 (kb = 0, sg = 2, sgm1 = 1)
    stepf< 1,true,true>(0,2,1, ARGS); stepf< 2,true,true>(0,2,1, ARGS);
    stepf< 3,true,true>(0,2,1, ARGS); stepf< 4,true,true>(0,2,1, ARGS);
    stepf< 5,true,true>(0,2,1, ARGS); stepf< 6,true,true>(0,2,1, ARGS);
    stepf< 7,true,true>(0,2,1, ARGS); stepf< 8,true,true>(0,2,1, ARGS);
    stepf< 9,true,true>(0,2,1, ARGS); stepf<10,true,true>(0,2,1, ARGS);
    stepf<11,true,true>(0,2,1, ARGS); stepf<12,true,true>(0,2,1, ARGS);
    stepf<13,true,true>(0,2,1, ARGS); stepf<14,true,true>(0,2,1, ARGS);
    stepf<15,true,true>(0,2,1, ARGS);

    // ---- main bodies kk = 16..495
#pragma clang loop unroll(disable)
    for (int kb = 16; kb <= 480; kb += 16) {
        if ((kb & 63) == 0) {
            float M = fmaxf(fmaxf(fmaxf(w10, w11), fmaxf(w12, w13)),
                            fmaxf(fmaxf(w20, w21), fmaxf(w22, w23)));
            #pragma unroll
            for (int m = 1; m < 64; m <<= 1) M = fmaxf(M, __shfl_xor(M, m));
            int e = ((__float_as_int(M) >> 23) & 255) - 127;
            float f = __int_as_float((127 - e) << 23);
            w10 *= f; w11 *= f; w12 *= f; w13 *= f;
            w20 *= f; w21 *= f; w22 *= f; w23 *= f;
            pd1 *= f; pd2 *= f;
            sig -= e;
        }
        const int sg = (kb >> 4) + 2, sgm1 = sg - 1;
        stepf< 0,true,true>(kb, sg, sgm1, ARGS); stepf< 1,true,true>(kb, sg, sgm1, ARGS);
        stepf< 2,true,true>(kb, sg, sgm1, ARGS); stepf< 3,true,true>(kb, sg, sgm1, ARGS);
        stepf< 4,true,true>(kb, sg, sgm1, ARGS); stepf< 5,true,true>(kb, sg, sgm1, ARGS);
        stepf< 6,true,true>(kb, sg, sgm1, ARGS); stepf< 7,true,true>(kb, sg, sgm1, ARGS);
        stepf< 8,true,true>(kb, sg, sgm1, ARGS); stepf< 9,true,true>(kb, sg, sgm1, ARGS);
        stepf<10,true,true>(kb, sg, sgm1, ARGS); stepf<11,true,true>(kb, sg, sgm1, ARGS);
        stepf<12,true,true>(kb, sg, sgm1, ARGS); stepf<13,true,true>(kb, sg, sgm1, ARGS);
        stepf<14,true,true>(kb, sg, sgm1, ARGS); stepf<15,true,true>(kb, sg, sgm1, ARGS);
    }

    // ---- epilogue kk = 496..510 (no staging; RQ refill while target <= 510)
    stepf< 0,false,true >(496,0,0, ARGS); stepf< 1,false,true >(496,0,0, ARGS);
    stepf< 2,false,true >(496,0,0, ARGS); stepf< 3,false,true >(496,0,0, ARGS);
    stepf< 4,false,true >(496,0,0, ARGS); stepf< 5,false,true >(496,0,0, ARGS);
    stepf< 6,false,true >(496,0,0, ARGS); stepf< 7,false,true >(496,0,0, ARGS);
    stepf< 8,false,true >(496,0,0, ARGS); stepf< 9,false,true >(496,0,0, ARGS);
    stepf<10,false,true >(496,0,0, ARGS); stepf<11,false,false>(496,0,0, ARGS);
    stepf<12,false,false>(496,0,0, ARGS); stepf<13,false,false>(496,0,0, ARGS);
    stepf<14,false,false>(496,0,0, ARGS);
#undef ARGS

    // corner cell (255,255): lane 63, E = sig - log2(w13), D = E * ln2
    if (t == 63) out[b] = ((float)sig - LOG2F(w13)) * LN2;
}

extern "C" void kernel_launch(void* const* d_in, const int* in_sizes, int n_in,
                              void* d_out, int out_size, void* d_ws, size_t ws_size,
                              hipStream_t stream) {
    const float* C = (const float*)d_in[0];
    float* out = (float*)d_out;
    dp_softmin_wave<<<512, 64, 0, stream>>>(C, out);
}